// Round 1
// baseline (1579.120 us; speedup 1.0000x reference)
//
#include <hip/hip_runtime.h>
#include <math.h>

#define DIMC 256
#define HW   16384
#define NB   8
#define HID  512
#define NE   4
#define RNK  128

// ---------------------------------------------------------------------------
// Kernel 1: per-(b,c) plane: xsum = sum(x), hsum = sum(gelu(highpass3x3(x)))
// ---------------------------------------------------------------------------
__global__ __launch_bounds__(256) void k_conv_reduce(const float* __restrict__ x,
                                                     float* __restrict__ xsum,
                                                     float* __restrict__ hsum) {
  __shared__ float s[HW];                    // 64 KB: the full 128x128 plane
  const int p = blockIdx.x;                  // plane index = b*DIMC + c
  const int tid = threadIdx.x;
  const float4* img4 = (const float4*)(x + (size_t)p * HW);
  float4* s4 = (float4*)s;
#pragma unroll
  for (int u = 0; u < 16; ++u) s4[tid + 256 * u] = img4[tid + 256 * u];
  __syncthreads();

  float xacc = 0.f, hacc = 0.f;
  for (int i = tid; i < HW; i += 256) {
    const int yy = i >> 7, xx = i & 127;
    const float c = s[i];
    float S = 0.f;
#pragma unroll
    for (int dy = -1; dy <= 1; ++dy) {
      const int y2 = yy + dy;
      if ((unsigned)y2 > 127u) continue;     // zero padding (SAME)
      const int base = y2 << 7;
      if (xx > 0)   S += s[base + xx - 1];
      S += s[base + xx];
      if (xx < 127) S += s[base + xx + 1];
    }
    const float v = 9.f * c - S;             // 8*center - neighbors
    hacc += 0.5f * v * (1.f + erff(v * 0.70710678118654752f));  // exact GELU
    xacc += c;
  }
  // wave reduce (64 lanes)
#pragma unroll
  for (int off = 32; off > 0; off >>= 1) {
    xacc += __shfl_down(xacc, off);
    hacc += __shfl_down(hacc, off);
  }
  __syncthreads();                           // all conv reads of s done
  const int wid = tid >> 6, lane = tid & 63;
  if (lane == 0) { s[wid] = xacc; s[8 + wid] = hacc; }
  __syncthreads();
  if (tid == 0) {
    xsum[p] = s[0] + s[1] + s[2] + s[3];
    hsum[p] = s[8] + s[9] + s[10] + s[11];
  }
}

// ---------------------------------------------------------------------------
// Kernel 2: gating MLP + softmax + top-2 (single block)
// ---------------------------------------------------------------------------
__global__ __launch_bounds__(256) void k_gate(
    const float* __restrict__ xsum, const float* __restrict__ hsum,
    const float* __restrict__ w1, const float* __restrict__ b1,
    const float* __restrict__ w2, const float* __restrict__ b2,
    const float* __restrict__ gw, const float* __restrict__ fgw,
    float* __restrict__ gates, float* __restrict__ gsumv, int* __restrict__ sel) {
  __shared__ float sh[NB][DIMC], sp[NB][DIMC], st1[NB][HID], sfe[NB][DIMC];
  __shared__ float slog[NB][NE];
  const int tid = threadIdx.x;
  const float inv = 1.f / 16384.f;
  for (int j = tid; j < NB * DIMC; j += 256) {
    sh[j >> 8][j & 255] = hsum[j] * inv;
    sp[j >> 8][j & 255] = xsum[j] * inv;
  }
  __syncthreads();
  // t1 = gelu(h @ w1^T + b1)   [8,512]
  for (int j = tid; j < NB * HID; j += 256) {
    const int b = j >> 9, o = j & 511;
    const float* wr = w1 + (size_t)o * DIMC;
    float acc = b1[o];
    for (int d = 0; d < DIMC; d += 4) {
      const float4 w = *(const float4*)(wr + d);
      const float4 h = *(const float4*)(&sh[b][d]);
      acc += h.x * w.x + h.y * w.y + h.z * w.z + h.w * w.w;
    }
    st1[b][o] = 0.5f * acc * (1.f + erff(acc * 0.70710678118654752f));
  }
  __syncthreads();
  // fe = t1 @ w2^T + b2        [8,256]
  for (int j = tid; j < NB * DIMC; j += 256) {
    const int b = j >> 8, o = j & 255;
    const float* wr = w2 + (size_t)o * HID;
    float acc = b2[o];
    for (int d = 0; d < HID; d += 4) {
      const float4 w = *(const float4*)(wr + d);
      const float4 h = *(const float4*)(&st1[b][d]);
      acc += h.x * w.x + h.y * w.y + h.z * w.z + h.w * w.w;
    }
    sfe[b][o] = acc;
  }
  __syncthreads();
  // logits[b,e] = pooled·gw[e] + fe·fgw[e]
  if (tid < NB * NE) {
    const int b = tid >> 2, e = tid & 3;
    const float* g1 = gw + e * DIMC;
    const float* g2 = fgw + e * DIMC;
    float acc = 0.f;
    for (int d = 0; d < DIMC; ++d) acc += sp[b][d] * g1[d] + sfe[b][d] * g2[d];
    slog[b][e] = acc;
  }
  __syncthreads();
  if (tid < NB) {
    const int b = tid;
    float l[4] = {slog[b][0], slog[b][1], slog[b][2], slog[b][3]};
    const float m = fmaxf(fmaxf(l[0], l[1]), fmaxf(l[2], l[3]));
    float g[4];
    float ssum = 0.f;
    for (int e = 0; e < 4; ++e) { g[e] = expf(l[e] - m); ssum += g[e]; }
    for (int e = 0; e < 4; ++e) g[e] /= ssum;
    // top-2, ties -> lower index (matches lax.top_k)
    int i1 = 0;
    for (int e = 1; e < 4; ++e) if (g[e] > g[i1]) i1 = e;
    int i2 = -1;
    for (int e = 0; e < 4; ++e) { if (e == i1) continue; if (i2 < 0 || g[e] > g[i2]) i2 = e; }
    for (int e = 0; e < 4; ++e)
      gates[b * 4 + e] = (e == i1) ? g[i1] : ((e == i2) ? g[i2] : 0.f);
    gsumv[b] = g[i1] + g[i2];
    sel[b * 2 + 0] = i1;
    sel[b * 2 + 1] = i2;
  }
}

// ---------------------------------------------------------------------------
// Kernel 3: Q2[e,o,r] = sum_d Wp[o,d] * p2[e,d,r]
// ---------------------------------------------------------------------------
__global__ __launch_bounds__(128) void k_q2(const float* __restrict__ wp,
                                            const float* __restrict__ p2,
                                            float* __restrict__ q2) {
  const int eo = blockIdx.x;                 // e*256 + o
  const int e = eo >> 8, o = eo & 255;
  const int r = threadIdx.x;
  const float* p2e = p2 + (size_t)e * DIMC * RNK;
  const float* wrow = wp + (size_t)o * DIMC;
  float acc = 0.f;
  for (int d = 0; d < DIMC; ++d) acc += wrow[d] * p2e[d * RNK + r];
  q2[(size_t)eo * RNK + r] = acc;
}

// ---------------------------------------------------------------------------
// Kernel 4: assemble per-batch GEMM weights A1 [512,256], A2 [256,256], A3 [256,256]
// A1 rows 0-255: p0[e1];p0[e2]; rows 256-511: gsum*Wp  (shortcut, fused)
// A2: p1[e1];p1[e2].   A3 cols 0-127: g1*Q2[e1], cols 128-255: g2*Q2[e2]
// ---------------------------------------------------------------------------
__global__ __launch_bounds__(256) void k_build(
    const float* __restrict__ p0, const float* __restrict__ p1,
    const float* __restrict__ wp, const float* __restrict__ q2,
    const float* __restrict__ gates, const float* __restrict__ gsumv,
    const int* __restrict__ sel,
    float* __restrict__ A1, float* __restrict__ A2, float* __restrict__ A3) {
  const int N1 = NB * 512 * 256;
  const int N2 = NB * 256 * 256;
  const int N3 = NB * 256 * 256;
  for (int idx = blockIdx.x * 256 + threadIdx.x; idx < N1 + N2 + N3;
       idx += gridDim.x * 256) {
    if (idx < N1) {
      const int b = idx >> 17;
      const int row = (idx >> 8) & 511;
      const int d = idx & 255;
      float v;
      if (row < 256) {
        const int e = sel[b * 2 + (row >> 7)];
        v = p0[((size_t)e * 128 + (row & 127)) * 256 + d];
      } else {
        v = gsumv[b] * wp[(row - 256) * 256 + d];
      }
      A1[idx] = v;
    } else if (idx < N1 + N2) {
      const int j = idx - N1;
      const int b = j >> 16;
      const int row = (j >> 8) & 255;
      const int d = j & 255;
      const int e = sel[b * 2 + (row >> 7)];
      A2[j] = p1[((size_t)e * 128 + (row & 127)) * 256 + d];
    } else {
      const int j = idx - N1 - N2;
      const int b = j >> 16;
      const int o = (j >> 8) & 255;
      const int rp = j & 255;
      const int e = sel[b * 2 + (rp >> 7)];
      A3[j] = gates[b * 4 + e] * q2[((size_t)e * 256 + o) * RNK + (rp & 127)];
    }
  }
}

// ---------------------------------------------------------------------------
// Kernel 5: fused main compute per 32-pixel tile
// ---------------------------------------------------------------------------
__device__ __forceinline__ void gemm_tile(float acc[8][4], const float* __restrict__ A,
                                          const float* __restrict__ Bl,
                                          const int r0, const int n0) {
  for (int k = 0; k < 256; k += 4) {
    float blv[16];
#pragma unroll
    for (int kk = 0; kk < 4; ++kk) {
      const float4 v = *(const float4*)(Bl + (k + kk) * 32 + n0);
      blv[kk * 4 + 0] = v.x; blv[kk * 4 + 1] = v.y;
      blv[kk * 4 + 2] = v.z; blv[kk * 4 + 3] = v.w;
    }
#pragma unroll
    for (int i = 0; i < 8; ++i) {
      const float4 a = *(const float4*)(A + (size_t)(r0 + i) * 256 + k);
#pragma unroll
      for (int j = 0; j < 4; ++j) {
        acc[i][j] = fmaf(a.x, blv[0 + j],  acc[i][j]);
        acc[i][j] = fmaf(a.y, blv[4 + j],  acc[i][j]);
        acc[i][j] = fmaf(a.z, blv[8 + j],  acc[i][j]);
        acc[i][j] = fmaf(a.w, blv[12 + j], acc[i][j]);
      }
    }
  }
}

__global__ __launch_bounds__(256) void k_main(
    const float* __restrict__ x, const float* __restrict__ shr,
    const float* __restrict__ A1, const float* __restrict__ A2,
    const float* __restrict__ A3, float* __restrict__ out) {
  __shared__ float tin[DIMC * 32];           // 32 KB input tile
  __shared__ float ty[DIMC * 32];            // 32 KB y tile
  const int bidx = blockIdx.x;
  const int b = bidx >> 9;                   // 512 tiles per batch
  const int nb0 = (bidx & 511) * 32;
  const int tid = threadIdx.x;
  const int n0 = (tid & 7) * 4;              // 8 col-groups x 4 cols
  const int r0 = (tid >> 3) * 8;             // 32 row-groups x 8 rows
  const float* A1b = A1 + (size_t)b * 512 * 256;
  const float* A2b = A2 + (size_t)b * 256 * 256;
  const float* A3b = A3 + (size_t)b * 256 * 256;
  const size_t plane = (size_t)b * DIMC * HW + nb0;

  // phase A: shared tile -> LDS; bb = A2 @ shared
#pragma unroll
  for (int u = 0; u < 8; ++u) {
    const int f = tid + u * 256;
    const int d = f >> 3, nq = (f & 7) * 4;
    *(float4*)(tin + d * 32 + nq) = *(const float4*)(shr + plane + (size_t)d * HW + nq);
  }
  __syncthreads();
  float accB[8][4];
#pragma unroll
  for (int i = 0; i < 8; ++i)
#pragma unroll
    for (int j = 0; j < 4; ++j) accB[i][j] = 0.f;
  gemm_tile(accB, A2b, tin, r0, n0);
  __syncthreads();

  // phase B: x tile -> LDS; a = A1[0:256] @ x
#pragma unroll
  for (int u = 0; u < 8; ++u) {
    const int f = tid + u * 256;
    const int d = f >> 3, nq = (f & 7) * 4;
    *(float4*)(tin + d * 32 + nq) = *(const float4*)(x + plane + (size_t)d * HW + nq);
  }
  __syncthreads();
  float accA[8][4];
#pragma unroll
  for (int i = 0; i < 8; ++i)
#pragma unroll
    for (int j = 0; j < 4; ++j) accA[i][j] = 0.f;
  gemm_tile(accA, A1b, tin, r0, n0);

  // y = a * silu(bb) -> LDS
#pragma unroll
  for (int i = 0; i < 8; ++i)
#pragma unroll
    for (int j = 0; j < 4; ++j) {
      const float bb = accB[i][j];
      ty[(r0 + i) * 32 + n0 + j] = accA[i][j] * (bb / (1.f + __expf(-bb)));
    }
  __syncthreads();

  // phase C: out = A3 @ y + A1[256:512] @ x  (shortcut rows)
  float accO[8][4];
#pragma unroll
  for (int i = 0; i < 8; ++i)
#pragma unroll
    for (int j = 0; j < 4; ++j) accO[i][j] = 0.f;
  gemm_tile(accO, A3b, ty, r0, n0);
  gemm_tile(accO, A1b + 256 * 256, tin, r0, n0);

#pragma unroll
  for (int i = 0; i < 8; ++i) {
    const float4 v = make_float4(accO[i][0], accO[i][1], accO[i][2], accO[i][3]);
    *(float4*)(out + plane + (size_t)(r0 + i) * HW + n0) = v;
  }
}

// ---------------------------------------------------------------------------
extern "C" void kernel_launch(void* const* d_in, const int* in_sizes, int n_in,
                              void* d_out, int out_size, void* d_ws, size_t ws_size,
                              hipStream_t stream) {
  (void)in_sizes; (void)n_in; (void)out_size; (void)ws_size;
  const float* x   = (const float*)d_in[0];
  const float* shr = (const float*)d_in[1];
  const float* w1  = (const float*)d_in[2];
  const float* b1  = (const float*)d_in[3];
  const float* w2  = (const float*)d_in[4];
  const float* b2  = (const float*)d_in[5];
  const float* gw  = (const float*)d_in[6];
  const float* fgw = (const float*)d_in[7];
  const float* p0  = (const float*)d_in[8];
  const float* p1  = (const float*)d_in[9];
  const float* p2  = (const float*)d_in[10];
  const float* wp  = (const float*)d_in[11];
  float* out = (float*)d_out;

  float* ws    = (float*)d_ws;
  float* xsum  = ws;                         // 2048
  float* hsum  = ws + 2048;                  // 2048
  float* gates = ws + 4096;                  // 32
  float* gsumv = ws + 4128;                  // 8
  int*   sel   = (int*)(ws + 4136);          // 16 ints
  float* q2    = ws + 4152;                  // 4*256*128 = 131072
  float* A1    = q2 + 4 * 256 * 128;         // 8*512*256
  float* A2    = A1 + 8 * 512 * 256;         // 8*256*256
  float* A3    = A2 + 8 * 256 * 256;         // 8*256*256

  k_conv_reduce<<<NB * DIMC, 256, 0, stream>>>(x, xsum, hsum);
  k_gate<<<1, 256, 0, stream>>>(xsum, hsum, w1, b1, w2, b2, gw, fgw, gates, gsumv, sel);
  k_q2<<<NE * DIMC, 128, 0, stream>>>(wp, p2, q2);
  k_build<<<2048, 256, 0, stream>>>(p0, p1, wp, q2, gates, gsumv, sel, A1, A2, A3);
  k_main<<<NB * 512, 256, 0, stream>>>(x, shr, A1, A2, A3, out);
}

// Round 2
// 573.588 us; speedup vs baseline: 2.7531x; 2.7531x over previous
//
#include <hip/hip_runtime.h>
#include <math.h>

#define DIMC 256
#define HW   16384
#define NB   8
#define HID  512
#define NE   4
#define RNK  128

typedef __bf16 bf16x8 __attribute__((ext_vector_type(8)));
typedef float  f32x4  __attribute__((ext_vector_type(4)));

__device__ __forceinline__ unsigned short f2bf(float f) {
  unsigned u = __builtin_bit_cast(unsigned, f);
  u += 0x7FFFu + ((u >> 16) & 1u);          // round-to-nearest-even
  return (unsigned short)(u >> 16);
}
__device__ __forceinline__ unsigned pack2(float a, float b) {
  return (unsigned)f2bf(a) | ((unsigned)f2bf(b) << 16);
}

// ---------------------------------------------------------------------------
// Kernel 1: per-(b,c) plane: xsum = sum(x), hsum = sum(gelu(highpass3x3(x)))
// ---------------------------------------------------------------------------
__global__ __launch_bounds__(256) void k_conv_reduce(const float* __restrict__ x,
                                                     float* __restrict__ xsum,
                                                     float* __restrict__ hsum) {
  __shared__ float s[HW];
  const int p = blockIdx.x;
  const int tid = threadIdx.x;
  const float4* img4 = (const float4*)(x + (size_t)p * HW);
  float4* s4 = (float4*)s;
#pragma unroll
  for (int u = 0; u < 16; ++u) s4[tid + 256 * u] = img4[tid + 256 * u];
  __syncthreads();

  float xacc = 0.f, hacc = 0.f;
  for (int i = tid; i < HW; i += 256) {
    const int yy = i >> 7, xx = i & 127;
    const float c = s[i];
    float S = 0.f;
#pragma unroll
    for (int dy = -1; dy <= 1; ++dy) {
      const int y2 = yy + dy;
      if ((unsigned)y2 > 127u) continue;
      const int base = y2 << 7;
      if (xx > 0)   S += s[base + xx - 1];
      S += s[base + xx];
      if (xx < 127) S += s[base + xx + 1];
    }
    const float v = 9.f * c - S;
    hacc += 0.5f * v * (1.f + erff(v * 0.70710678118654752f));
    xacc += c;
  }
#pragma unroll
  for (int off = 32; off > 0; off >>= 1) {
    xacc += __shfl_down(xacc, off);
    hacc += __shfl_down(hacc, off);
  }
  __syncthreads();
  const int wid = tid >> 6, lane = tid & 63;
  if (lane == 0) { s[wid] = xacc; s[8 + wid] = hacc; }
  __syncthreads();
  if (tid == 0) {
    xsum[p] = s[0] + s[1] + s[2] + s[3];
    hsum[p] = s[8] + s[9] + s[10] + s[11];
  }
}

// ---------------------------------------------------------------------------
// Kernel 2: gating MLP + softmax + top-2 (single block)
// ---------------------------------------------------------------------------
__global__ __launch_bounds__(256) void k_gate(
    const float* __restrict__ xsum, const float* __restrict__ hsum,
    const float* __restrict__ w1, const float* __restrict__ b1,
    const float* __restrict__ w2, const float* __restrict__ b2,
    const float* __restrict__ gw, const float* __restrict__ fgw,
    float* __restrict__ gates, float* __restrict__ gsumv, int* __restrict__ sel) {
  __shared__ float sh[NB][DIMC], sp[NB][DIMC], st1[NB][HID], sfe[NB][DIMC];
  __shared__ float slog[NB][NE];
  const int tid = threadIdx.x;
  const float inv = 1.f / 16384.f;
  for (int j = tid; j < NB * DIMC; j += 256) {
    sh[j >> 8][j & 255] = hsum[j] * inv;
    sp[j >> 8][j & 255] = xsum[j] * inv;
  }
  __syncthreads();
  for (int j = tid; j < NB * HID; j += 256) {
    const int b = j >> 9, o = j & 511;
    const float* wr = w1 + (size_t)o * DIMC;
    float acc = b1[o];
    for (int d = 0; d < DIMC; d += 4) {
      const float4 w = *(const float4*)(wr + d);
      const float4 h = *(const float4*)(&sh[b][d]);
      acc += h.x * w.x + h.y * w.y + h.z * w.z + h.w * w.w;
    }
    st1[b][o] = 0.5f * acc * (1.f + erff(acc * 0.70710678118654752f));
  }
  __syncthreads();
  for (int j = tid; j < NB * DIMC; j += 256) {
    const int b = j >> 8, o = j & 255;
    const float* wr = w2 + (size_t)o * HID;
    float acc = b2[o];
    for (int d = 0; d < HID; d += 4) {
      const float4 w = *(const float4*)(wr + d);
      const float4 h = *(const float4*)(&st1[b][d]);
      acc += h.x * w.x + h.y * w.y + h.z * w.z + h.w * w.w;
    }
    sfe[b][o] = acc;
  }
  __syncthreads();
  if (tid < NB * NE) {
    const int b = tid >> 2, e = tid & 3;
    const float* g1 = gw + e * DIMC;
    const float* g2 = fgw + e * DIMC;
    float acc = 0.f;
    for (int d = 0; d < DIMC; ++d) acc += sp[b][d] * g1[d] + sfe[b][d] * g2[d];
    slog[b][e] = acc;
  }
  __syncthreads();
  if (tid < NB) {
    const int b = tid;
    float l[4] = {slog[b][0], slog[b][1], slog[b][2], slog[b][3]};
    const float m = fmaxf(fmaxf(l[0], l[1]), fmaxf(l[2], l[3]));
    float g[4];
    float ssum = 0.f;
    for (int e = 0; e < 4; ++e) { g[e] = expf(l[e] - m); ssum += g[e]; }
    for (int e = 0; e < 4; ++e) g[e] /= ssum;
    int i1 = 0;
    for (int e = 1; e < 4; ++e) if (g[e] > g[i1]) i1 = e;
    int i2 = -1;
    for (int e = 0; e < 4; ++e) { if (e == i1) continue; if (i2 < 0 || g[e] > g[i2]) i2 = e; }
    for (int e = 0; e < 4; ++e)
      gates[b * 4 + e] = (e == i1) ? g[i1] : ((e == i2) ? g[i2] : 0.f);
    gsumv[b] = g[i1] + g[i2];
    sel[b * 2 + 0] = i1;
    sel[b * 2 + 1] = i2;
  }
}

// ---------------------------------------------------------------------------
// Kernel 3: Q2[e,o,r] = sum_d Wp[o,d] * p2[e,d,r]   (fp32)
// ---------------------------------------------------------------------------
__global__ __launch_bounds__(128) void k_q2(const float* __restrict__ wp,
                                            const float* __restrict__ p2,
                                            float* __restrict__ q2) {
  const int eo = blockIdx.x;
  const int e = eo >> 8, o = eo & 255;
  const int r = threadIdx.x;
  const float* p2e = p2 + (size_t)e * DIMC * RNK;
  const float* wrow = wp + (size_t)o * DIMC;
  float acc = 0.f;
  for (int d = 0; d < DIMC; ++d) acc += wrow[d] * p2e[d * RNK + r];
  q2[(size_t)eo * RNK + r] = acc;
}

// ---------------------------------------------------------------------------
// Kernel 4: assemble per-batch bf16 GEMM weights (u32-pair packed writes)
// A1 [b][256][256] rows = p0[e1];p0[e2]
// A2 [b][256][256] rows = p1[e1];p1[e2]
// A3 [b][256][512] cols 0-255 = gate-scaled Q2, cols 256-511 = gsum*Wp
// ---------------------------------------------------------------------------
__global__ __launch_bounds__(256) void k_build(
    const float* __restrict__ p0, const float* __restrict__ p1,
    const float* __restrict__ wp, const float* __restrict__ q2,
    const float* __restrict__ gates, const float* __restrict__ gsumv,
    const int* __restrict__ sel,
    unsigned* __restrict__ A1u, unsigned* __restrict__ A2u,
    unsigned* __restrict__ A3u) {
  const int P1 = NB * 256 * 128;           // u32 pairs in A1
  const int P2 = P1;
  const int P3 = NB * 256 * 256;           // pairs in A3
  for (int pi = blockIdx.x * 256 + threadIdx.x; pi < P1 + P2 + P3;
       pi += gridDim.x * 256) {
    if (pi < P1) {
      const int b = pi >> 15;
      const int row = (pi >> 7) & 255;
      const int d = (pi & 127) * 2;
      const int e = sel[b * 2 + (row >> 7)];
      const float* src = p0 + ((size_t)e * 128 + (row & 127)) * 256 + d;
      A1u[pi] = pack2(src[0], src[1]);
    } else if (pi < P1 + P2) {
      const int j = pi - P1;
      const int b = j >> 15;
      const int row = (j >> 7) & 255;
      const int d = (j & 127) * 2;
      const int e = sel[b * 2 + (row >> 7)];
      const float* src = p1 + ((size_t)e * 128 + (row & 127)) * 256 + d;
      A2u[j] = pack2(src[0], src[1]);
    } else {
      const int j = pi - P1 - P2;
      const int b = j >> 16;
      const int o = (j >> 8) & 255;
      const int c = (j & 255) * 2;
      float v0, v1;
      if (c < 256) {
        const int e = sel[b * 2 + (c >> 7)];
        const float gsc = gates[b * 4 + e];
        const float* qq = q2 + ((size_t)e * 256 + o) * RNK + (c & 127);
        v0 = gsc * qq[0]; v1 = gsc * qq[1];
      } else {
        const float gs = gsumv[b];
        const float* wr = wp + (size_t)o * DIMC + (c - 256);
        v0 = gs * wr[0]; v1 = gs * wr[1];
      }
      A3u[j] = pack2(v0, v1);
    }
  }
}

// ---------------------------------------------------------------------------
// Kernel 5: fused MFMA main compute. 512 thr (8 waves), 64-pixel tiles.
// LDS fragment layout: [dblk = k/8][p ^ (dblk&7)][8 bf16]  (32 KB per tensor)
// ---------------------------------------------------------------------------
__global__ __launch_bounds__(512) void k_main_mfma(
    const float* __restrict__ x, const float* __restrict__ shr,
    const unsigned short* __restrict__ A1b, const unsigned short* __restrict__ A2b,
    const unsigned short* __restrict__ A3b, float* __restrict__ out) {
  __shared__ unsigned short XF[16384];      // x tile, 32 KB
  __shared__ unsigned short SF[16384];      // shared tile, then Y tile
  const int tid = threadIdx.x;
  const int b = blockIdx.x & 7;             // batch on fixed XCD (round-robin)
  const int tile = blockIdx.x >> 3;
  const int nb0 = tile * 64;
  const int wave = tid >> 6;
  const int lane = tid & 63;
  const int li = lane & 15;
  const int g = lane >> 4;
  const int wrow = wave * 32;
  const size_t pbase = (size_t)b * DIMC * HW + nb0;

  // ---- stage x, shr -> bf16 fragment-layout LDS ----
  {
    const float* srcs[2] = {x + pbase, shr + pbase};
    unsigned short* dsts[2] = {XF, SF};
#pragma unroll
    for (int tsel = 0; tsel < 2; ++tsel) {
      const float* src = srcs[tsel];
      unsigned short* dst = dsts[tsel];
#pragma unroll
      for (int u = 0; u < 2; ++u) {
        const int unit = u * 512 + tid;     // 1024 units: 64 d-quads x 16 p-grps
        const int pg = unit & 15;
        const int dq = unit >> 4;
        const int d0 = dq * 4;
        const float* gp = src + (size_t)d0 * HW + pg * 4;
        f32x4 r0 = *(const f32x4*)(gp);
        f32x4 r1 = *(const f32x4*)(gp + HW);
        f32x4 r2 = *(const f32x4*)(gp + 2 * HW);
        f32x4 r3 = *(const f32x4*)(gp + 3 * HW);
        const int dblk = dq >> 1;
        const int off = (dq & 1) * 4;
        const int s = dblk & 7;
#pragma unroll
        for (int i = 0; i < 4; ++i) {
          const int p = pg * 4 + i;
          const int idx = dblk * 512 + ((p ^ s) * 8) + off;
          uint2 w;
          w.x = pack2(r0[i], r1[i]);
          w.y = pack2(r2[i], r3[i]);
          *(uint2*)(&dst[idx]) = w;
        }
      }
    }
  }
  __syncthreads();

  const int be = (li ^ g) * 8 + g * 512;    // lane part of B-frag index

  // ---- GEMM2: bb = A2 @ shared (regs) ----
  f32x4 accB[2][4];
#pragma unroll
  for (int rf = 0; rf < 2; ++rf)
#pragma unroll
    for (int pb = 0; pb < 4; ++pb) accB[rf][pb] = (f32x4)0.f;
  {
    const unsigned short* A0 = A2b + ((size_t)b * 256 + wrow + li) * 256;
    const unsigned short* A1r = A0 + 16 * 256;
#pragma unroll
    for (int ks = 0; ks < 8; ++ks) {
      const int ib = ((ks & 1) ? (be ^ 32) : be) + ks * 2048;
      bf16x8 bf[4];
#pragma unroll
      for (int pb = 0; pb < 4; ++pb) bf[pb] = *(const bf16x8*)(&SF[ib + pb * 128]);
      bf16x8 a0 = *(const bf16x8*)(A0 + ks * 32 + g * 8);
      bf16x8 a1 = *(const bf16x8*)(A1r + ks * 32 + g * 8);
#pragma unroll
      for (int pb = 0; pb < 4; ++pb) {
        accB[0][pb] = __builtin_amdgcn_mfma_f32_16x16x32_bf16(a0, bf[pb], accB[0][pb], 0, 0, 0);
        accB[1][pb] = __builtin_amdgcn_mfma_f32_16x16x32_bf16(a1, bf[pb], accB[1][pb], 0, 0, 0);
      }
    }
  }
  __syncthreads();                          // all SF reads done

  // ---- GEMM1a: a = A1 @ x (regs) ----
  f32x4 accA[2][4];
#pragma unroll
  for (int rf = 0; rf < 2; ++rf)
#pragma unroll
    for (int pb = 0; pb < 4; ++pb) accA[rf][pb] = (f32x4)0.f;
  {
    const unsigned short* A0 = A1b + ((size_t)b * 256 + wrow + li) * 256;
    const unsigned short* A1r = A0 + 16 * 256;
#pragma unroll
    for (int ks = 0; ks < 8; ++ks) {
      const int ib = ((ks & 1) ? (be ^ 32) : be) + ks * 2048;
      bf16x8 bf[4];
#pragma unroll
      for (int pb = 0; pb < 4; ++pb) bf[pb] = *(const bf16x8*)(&XF[ib + pb * 128]);
      bf16x8 a0 = *(const bf16x8*)(A0 + ks * 32 + g * 8);
      bf16x8 a1 = *(const bf16x8*)(A1r + ks * 32 + g * 8);
#pragma unroll
      for (int pb = 0; pb < 4; ++pb) {
        accA[0][pb] = __builtin_amdgcn_mfma_f32_16x16x32_bf16(a0, bf[pb], accA[0][pb], 0, 0, 0);
        accA[1][pb] = __builtin_amdgcn_mfma_f32_16x16x32_bf16(a1, bf[pb], accA[1][pb], 0, 0, 0);
      }
    }
  }

  // ---- y = a * silu(bb) -> SF (bf16 frag layout, rows = wave's own rows) ----
#pragma unroll
  for (int rf = 0; rf < 2; ++rf) {
    const int r0 = wrow + rf * 16 + g * 4;
    const int ydblk = r0 >> 3;
    const int ys = ydblk & 7;
    const int yoff = (g & 1) * 4;
#pragma unroll
    for (int pb = 0; pb < 4; ++pb) {
      const int p = pb * 16 + li;
      f32x4 aa = accA[rf][pb], bb = accB[rf][pb];
      float y0 = aa[0] * (bb[0] / (1.f + __expf(-bb[0])));
      float y1 = aa[1] * (bb[1] / (1.f + __expf(-bb[1])));
      float y2 = aa[2] * (bb[2] / (1.f + __expf(-bb[2])));
      float y3 = aa[3] * (bb[3] / (1.f + __expf(-bb[3])));
      const int idx = ydblk * 512 + ((p ^ ys) * 8) + yoff;
      uint2 w;
      w.x = pack2(y0, y1);
      w.y = pack2(y2, y3);
      *(uint2*)(&SF[idx]) = w;
    }
  }
  __syncthreads();                          // Y ready

  // ---- GEMM3': out = [A3 | gsum*Wp] @ [y; x]  (K = 512) ----
  f32x4 accO[2][4];
#pragma unroll
  for (int rf = 0; rf < 2; ++rf)
#pragma unroll
    for (int pb = 0; pb < 4; ++pb) accO[rf][pb] = (f32x4)0.f;
  {
    const unsigned short* A0 = A3b + ((size_t)b * 256 + wrow + li) * 512;
    const unsigned short* A1r = A0 + 16 * 512;
#pragma unroll
    for (int ks = 0; ks < 16; ++ks) {
      const int kk = ks & 7;
      const unsigned short* Bsrc = (ks < 8) ? SF : XF;
      const int ib = ((kk & 1) ? (be ^ 32) : be) + kk * 2048;
      bf16x8 bf[4];
#pragma unroll
      for (int pb = 0; pb < 4; ++pb) bf[pb] = *(const bf16x8*)(&Bsrc[ib + pb * 128]);
      bf16x8 a0 = *(const bf16x8*)(A0 + ks * 32 + g * 8);
      bf16x8 a1 = *(const bf16x8*)(A1r + ks * 32 + g * 8);
#pragma unroll
      for (int pb = 0; pb < 4; ++pb) {
        accO[0][pb] = __builtin_amdgcn_mfma_f32_16x16x32_bf16(a0, bf[pb], accO[0][pb], 0, 0, 0);
        accO[1][pb] = __builtin_amdgcn_mfma_f32_16x16x32_bf16(a1, bf[pb], accO[1][pb], 0, 0, 0);
      }
    }
  }

  // ---- store out (fp32) ----
  float* obase = out + pbase;
#pragma unroll
  for (int rf = 0; rf < 2; ++rf) {
    const int r0 = wrow + rf * 16 + g * 4;
#pragma unroll
    for (int pb = 0; pb < 4; ++pb) {
      const int p = pb * 16 + li;
#pragma unroll
      for (int i = 0; i < 4; ++i)
        obase[(size_t)(r0 + i) * HW + p] = accO[rf][pb][i];
    }
  }
}

// ---------------------------------------------------------------------------
extern "C" void kernel_launch(void* const* d_in, const int* in_sizes, int n_in,
                              void* d_out, int out_size, void* d_ws, size_t ws_size,
                              hipStream_t stream) {
  (void)in_sizes; (void)n_in; (void)out_size; (void)ws_size;
  const float* x   = (const float*)d_in[0];
  const float* shr = (const float*)d_in[1];
  const float* w1  = (const float*)d_in[2];
  const float* b1  = (const float*)d_in[3];
  const float* w2  = (const float*)d_in[4];
  const float* b2  = (const float*)d_in[5];
  const float* gw  = (const float*)d_in[6];
  const float* fgw = (const float*)d_in[7];
  const float* p0  = (const float*)d_in[8];
  const float* p1  = (const float*)d_in[9];
  const float* p2  = (const float*)d_in[10];
  const float* wp  = (const float*)d_in[11];
  float* out = (float*)d_out;

  float* ws    = (float*)d_ws;
  float* xsum  = ws;                         // 2048 f32
  float* hsum  = ws + 2048;                  // 2048 f32
  float* gates = ws + 4096;                  // 32 f32
  float* gsumv = ws + 4128;                  // 8 f32
  int*   sel   = (int*)(ws + 4136);          // 16 ints
  float* q2    = ws + 4152;                  // 131072 f32
  unsigned* A1u = (unsigned*)(ws + 135224);  // 262144 u32 (bf16 pairs)
  unsigned* A2u = A1u + NB * 256 * 128;      // 262144 u32
  unsigned* A3u = A2u + NB * 256 * 128;      // 524288 u32

  k_conv_reduce<<<NB * DIMC, 256, 0, stream>>>(x, xsum, hsum);
  k_gate<<<1, 256, 0, stream>>>(xsum, hsum, w1, b1, w2, b2, gw, fgw, gates, gsumv, sel);
  k_q2<<<NE * DIMC, 128, 0, stream>>>(wp, p2, q2);
  k_build<<<512, 256, 0, stream>>>(p0, p1, wp, q2, gates, gsumv, sel, A1u, A2u, A3u);
  k_main_mfma<<<2048, 512, 0, stream>>>(x, shr,
      (const unsigned short*)A1u, (const unsigned short*)A2u,
      (const unsigned short*)A3u, out);
}

// Round 3
// 344.123 us; speedup vs baseline: 4.5888x; 1.6668x over previous
//
#include <hip/hip_runtime.h>
#include <math.h>

#define DIMC 256
#define HW   16384
#define NB   8
#define HID  512
#define NE   4
#define RNK  128

typedef __bf16 bf16x8 __attribute__((ext_vector_type(8)));
typedef float  f32x4  __attribute__((ext_vector_type(4)));

__device__ __forceinline__ unsigned short f2bf(float f) {
  unsigned u = __builtin_bit_cast(unsigned, f);
  u += 0x7FFFu + ((u >> 16) & 1u);          // round-to-nearest-even
  return (unsigned short)(u >> 16);
}
__device__ __forceinline__ unsigned pack2(float a, float b) {
  return (unsigned)f2bf(a) | ((unsigned)f2bf(b) << 16);
}

// ---------------------------------------------------------------------------
// Kernel 1: per-(b,c) plane: xsum = sum(x), hsum = sum(gelu(highpass3x3(x)))
// ---------------------------------------------------------------------------
__global__ __launch_bounds__(256) void k_conv_reduce(const float* __restrict__ x,
                                                     float* __restrict__ xsum,
                                                     float* __restrict__ hsum) {
  __shared__ float s[HW];
  const int p = blockIdx.x;
  const int tid = threadIdx.x;
  const float4* img4 = (const float4*)(x + (size_t)p * HW);
  float4* s4 = (float4*)s;
#pragma unroll
  for (int u = 0; u < 16; ++u) s4[tid + 256 * u] = img4[tid + 256 * u];
  __syncthreads();

  float xacc = 0.f, hacc = 0.f;
  for (int i = tid; i < HW; i += 256) {
    const int yy = i >> 7, xx = i & 127;
    const float c = s[i];
    float S = 0.f;
#pragma unroll
    for (int dy = -1; dy <= 1; ++dy) {
      const int y2 = yy + dy;
      if ((unsigned)y2 > 127u) continue;
      const int base = y2 << 7;
      if (xx > 0)   S += s[base + xx - 1];
      S += s[base + xx];
      if (xx < 127) S += s[base + xx + 1];
    }
    const float v = 9.f * c - S;
    hacc += 0.5f * v * (1.f + erff(v * 0.70710678118654752f));
    xacc += c;
  }
#pragma unroll
  for (int off = 32; off > 0; off >>= 1) {
    xacc += __shfl_down(xacc, off);
    hacc += __shfl_down(hacc, off);
  }
  __syncthreads();
  const int wid = tid >> 6, lane = tid & 63;
  if (lane == 0) { s[wid] = xacc; s[8 + wid] = hacc; }
  __syncthreads();
  if (tid == 0) {
    xsum[p] = s[0] + s[1] + s[2] + s[3];
    hsum[p] = s[8] + s[9] + s[10] + s[11];
  }
}

// ---------------------------------------------------------------------------
// Gating stage A: t1[b,o] = gelu( (hsum[b]·w1[o]) / 16384 + b1[o] )
// one wave per output; 1024 blocks x 256 thr
// ---------------------------------------------------------------------------
__global__ __launch_bounds__(256) void k_gate_t1(
    const float* __restrict__ hsum, const float* __restrict__ w1,
    const float* __restrict__ b1, float* __restrict__ t1) {
  const int blk = blockIdx.x;
  const int b = blk >> 7;
  const int o = (blk & 127) * 4 + (threadIdx.x >> 6);
  const int lane = threadIdx.x & 63;
  const float4 h = *(const float4*)(hsum + b * DIMC + lane * 4);
  const float4 w = *(const float4*)(w1 + (size_t)o * DIMC + lane * 4);
  float acc = h.x * w.x + h.y * w.y + h.z * w.z + h.w * w.w;
#pragma unroll
  for (int off = 32; off > 0; off >>= 1) acc += __shfl_down(acc, off);
  if (lane == 0) {
    acc = acc * (1.f / 16384.f) + b1[o];
    t1[b * HID + o] = 0.5f * acc * (1.f + erff(acc * 0.70710678118654752f));
  }
}

// ---------------------------------------------------------------------------
// Gating stage B: fe[b,o] = t1[b]·w2[o] + b2[o]   (K=512)
// one wave per output; 512 blocks x 256 thr
// ---------------------------------------------------------------------------
__global__ __launch_bounds__(256) void k_gate_fe(
    const float* __restrict__ t1, const float* __restrict__ w2,
    const float* __restrict__ b2, float* __restrict__ fe) {
  const int blk = blockIdx.x;
  const int b = blk >> 6;
  const int o = (blk & 63) * 4 + (threadIdx.x >> 6);
  const int lane = threadIdx.x & 63;
  const float* tr = t1 + b * HID + lane * 8;
  const float* wr = w2 + (size_t)o * HID + lane * 8;
  const float4 ta = *(const float4*)tr,  tb = *(const float4*)(tr + 4);
  const float4 wa = *(const float4*)wr,  wb = *(const float4*)(wr + 4);
  float acc = ta.x * wa.x + ta.y * wa.y + ta.z * wa.z + ta.w * wa.w
            + tb.x * wb.x + tb.y * wb.y + tb.z * wb.z + tb.w * wb.w;
#pragma unroll
  for (int off = 32; off > 0; off >>= 1) acc += __shfl_down(acc, off);
  if (lane == 0) fe[b * DIMC + o] = acc + b2[o];
}

// ---------------------------------------------------------------------------
// Gating stage C: logits + softmax + top-2 (1 block, 4 waves: e = wave)
// ---------------------------------------------------------------------------
__global__ __launch_bounds__(256) void k_gate_fin(
    const float* __restrict__ xsum, const float* __restrict__ fe,
    const float* __restrict__ gw, const float* __restrict__ fgw,
    float* __restrict__ gates, float* __restrict__ gsumv, int* __restrict__ sel) {
  __shared__ float slog[NB][NE];
  const int wave = threadIdx.x >> 6, lane = threadIdx.x & 63;
  const int e = wave;
  const float4 g1 = *(const float4*)(gw + e * DIMC + lane * 4);
  const float4 g2 = *(const float4*)(fgw + e * DIMC + lane * 4);
  for (int b = 0; b < NB; ++b) {
    const float4 p = *(const float4*)(xsum + b * DIMC + lane * 4);
    const float4 f = *(const float4*)(fe + b * DIMC + lane * 4);
    float acc = (p.x * g1.x + p.y * g1.y + p.z * g1.z + p.w * g1.w) * (1.f / 16384.f)
              + f.x * g2.x + f.y * g2.y + f.z * g2.z + f.w * g2.w;
#pragma unroll
    for (int off = 32; off > 0; off >>= 1) acc += __shfl_down(acc, off);
    if (lane == 0) slog[b][e] = acc;
  }
  __syncthreads();
  if (threadIdx.x < NB) {
    const int b = threadIdx.x;
    float l[4] = {slog[b][0], slog[b][1], slog[b][2], slog[b][3]};
    const float m = fmaxf(fmaxf(l[0], l[1]), fmaxf(l[2], l[3]));
    float g[4];
    float ssum = 0.f;
    for (int e2 = 0; e2 < 4; ++e2) { g[e2] = expf(l[e2] - m); ssum += g[e2]; }
    for (int e2 = 0; e2 < 4; ++e2) g[e2] /= ssum;
    int i1 = 0;
    for (int e2 = 1; e2 < 4; ++e2) if (g[e2] > g[i1]) i1 = e2;
    int i2 = -1;
    for (int e2 = 0; e2 < 4; ++e2) {
      if (e2 == i1) continue;
      if (i2 < 0 || g[e2] > g[i2]) i2 = e2;
    }
    for (int e2 = 0; e2 < 4; ++e2)
      gates[b * 4 + e2] = (e2 == i1) ? g[i1] : ((e2 == i2) ? g[i2] : 0.f);
    gsumv[b] = g[i1] + g[i2];
    sel[b * 2 + 0] = i1;
    sel[b * 2 + 1] = i2;
  }
}

// ---------------------------------------------------------------------------
// Kernel 3: Q2[e,o,r] = sum_d Wp[o,d] * p2[e,d,r]   (fp32)
// ---------------------------------------------------------------------------
__global__ __launch_bounds__(128) void k_q2(const float* __restrict__ wp,
                                            const float* __restrict__ p2,
                                            float* __restrict__ q2) {
  const int eo = blockIdx.x;
  const int e = eo >> 8, o = eo & 255;
  const int r = threadIdx.x;
  const float* p2e = p2 + (size_t)e * DIMC * RNK;
  const float* wrow = wp + (size_t)o * DIMC;
  float acc = 0.f;
  for (int d = 0; d < DIMC; ++d) acc += wrow[d] * p2e[d * RNK + r];
  q2[(size_t)eo * RNK + r] = acc;
}

// ---------------------------------------------------------------------------
// Kernel 4: assemble per-batch bf16 GEMM weights (u32-pair packed writes)
// A1 [b][256][256] rows = p0[e1];p0[e2]
// A2 [b][256][256] rows = p1[e1];p1[e2]
// A3 [b][256][512] cols 0-255 = gate-scaled Q2, cols 256-511 = gsum*Wp
// ---------------------------------------------------------------------------
__global__ __launch_bounds__(256) void k_build(
    const float* __restrict__ p0, const float* __restrict__ p1,
    const float* __restrict__ wp, const float* __restrict__ q2,
    const float* __restrict__ gates, const float* __restrict__ gsumv,
    const int* __restrict__ sel,
    unsigned* __restrict__ A1u, unsigned* __restrict__ A2u,
    unsigned* __restrict__ A3u) {
  const int P1 = NB * 256 * 128;
  const int P2 = P1;
  const int P3 = NB * 256 * 256;
  for (int pi = blockIdx.x * 256 + threadIdx.x; pi < P1 + P2 + P3;
       pi += gridDim.x * 256) {
    if (pi < P1) {
      const int b = pi >> 15;
      const int row = (pi >> 7) & 255;
      const int d = (pi & 127) * 2;
      const int e = sel[b * 2 + (row >> 7)];
      const float* src = p0 + ((size_t)e * 128 + (row & 127)) * 256 + d;
      A1u[pi] = pack2(src[0], src[1]);
    } else if (pi < P1 + P2) {
      const int j = pi - P1;
      const int b = j >> 15;
      const int row = (j >> 7) & 255;
      const int d = (j & 127) * 2;
      const int e = sel[b * 2 + (row >> 7)];
      const float* src = p1 + ((size_t)e * 128 + (row & 127)) * 256 + d;
      A2u[j] = pack2(src[0], src[1]);
    } else {
      const int j = pi - P1 - P2;
      const int b = j >> 16;
      const int o = (j >> 8) & 255;
      const int c = (j & 255) * 2;
      float v0, v1;
      if (c < 256) {
        const int e = sel[b * 2 + (c >> 7)];
        const float gsc = gates[b * 4 + e];
        const float* qq = q2 + ((size_t)e * 256 + o) * RNK + (c & 127);
        v0 = gsc * qq[0]; v1 = gsc * qq[1];
      } else {
        const float gs = gsumv[b];
        const float* wr = wp + (size_t)o * DIMC + (c - 256);
        v0 = gs * wr[0]; v1 = gs * wr[1];
      }
      A3u[j] = pack2(v0, v1);
    }
  }
}

// ---------------------------------------------------------------------------
// Kernel 5: fused MFMA main compute. 512 thr (8 waves), 64-pixel tiles.
// LDS fragment layout: [dblk = k/8][p ^ (dblk&7)][8 bf16]  (32 KB per tensor)
// ---------------------------------------------------------------------------
__global__ __launch_bounds__(512) void k_main_mfma(
    const float* __restrict__ x, const float* __restrict__ shr,
    const unsigned short* __restrict__ A1b, const unsigned short* __restrict__ A2b,
    const unsigned short* __restrict__ A3b, float* __restrict__ out) {
  __shared__ unsigned short XF[16384];      // x tile, 32 KB
  __shared__ unsigned short SF[16384];      // shared tile, then Y tile
  const int tid = threadIdx.x;
  const int b = blockIdx.x & 7;
  const int tile = blockIdx.x >> 3;
  const int nb0 = tile * 64;
  const int wave = tid >> 6;
  const int lane = tid & 63;
  const int li = lane & 15;
  const int g = lane >> 4;
  const int wrow = wave * 32;
  const size_t pbase = (size_t)b * DIMC * HW + nb0;

  // ---- stage x, shr -> bf16 fragment-layout LDS ----
  {
    const float* srcs[2] = {x + pbase, shr + pbase};
    unsigned short* dsts[2] = {XF, SF};
#pragma unroll
    for (int tsel = 0; tsel < 2; ++tsel) {
      const float* src = srcs[tsel];
      unsigned short* dst = dsts[tsel];
#pragma unroll
      for (int u = 0; u < 2; ++u) {
        const int unit = u * 512 + tid;
        const int pg = unit & 15;
        const int dq = unit >> 4;
        const int d0 = dq * 4;
        const float* gp = src + (size_t)d0 * HW + pg * 4;
        f32x4 r0 = *(const f32x4*)(gp);
        f32x4 r1 = *(const f32x4*)(gp + HW);
        f32x4 r2 = *(const f32x4*)(gp + 2 * HW);
        f32x4 r3 = *(const f32x4*)(gp + 3 * HW);
        const int dblk = dq >> 1;
        const int off = (dq & 1) * 4;
        const int s = dblk & 7;
#pragma unroll
        for (int i = 0; i < 4; ++i) {
          const int p = pg * 4 + i;
          const int idx = dblk * 512 + ((p ^ s) * 8) + off;
          uint2 w;
          w.x = pack2(r0[i], r1[i]);
          w.y = pack2(r2[i], r3[i]);
          *(uint2*)(&dst[idx]) = w;
        }
      }
    }
  }
  __syncthreads();

  const int be = (li ^ g) * 8 + g * 512;

  // ---- GEMM2: bb = A2 @ shared (regs) ----
  f32x4 accB[2][4];
#pragma unroll
  for (int rf = 0; rf < 2; ++rf)
#pragma unroll
    for (int pb = 0; pb < 4; ++pb) accB[rf][pb] = (f32x4)0.f;
  {
    const unsigned short* A0 = A2b + ((size_t)b * 256 + wrow + li) * 256;
    const unsigned short* A1r = A0 + 16 * 256;
#pragma unroll
    for (int ks = 0; ks < 8; ++ks) {
      const int ib = ((ks & 1) ? (be ^ 32) : be) + ks * 2048;
      bf16x8 bf[4];
#pragma unroll
      for (int pb = 0; pb < 4; ++pb) bf[pb] = *(const bf16x8*)(&SF[ib + pb * 128]);
      bf16x8 a0 = *(const bf16x8*)(A0 + ks * 32 + g * 8);
      bf16x8 a1 = *(const bf16x8*)(A1r + ks * 32 + g * 8);
#pragma unroll
      for (int pb = 0; pb < 4; ++pb) {
        accB[0][pb] = __builtin_amdgcn_mfma_f32_16x16x32_bf16(a0, bf[pb], accB[0][pb], 0, 0, 0);
        accB[1][pb] = __builtin_amdgcn_mfma_f32_16x16x32_bf16(a1, bf[pb], accB[1][pb], 0, 0, 0);
      }
    }
  }
  __syncthreads();

  // ---- GEMM1a: a = A1 @ x (regs) ----
  f32x4 accA[2][4];
#pragma unroll
  for (int rf = 0; rf < 2; ++rf)
#pragma unroll
    for (int pb = 0; pb < 4; ++pb) accA[rf][pb] = (f32x4)0.f;
  {
    const unsigned short* A0 = A1b + ((size_t)b * 256 + wrow + li) * 256;
    const unsigned short* A1r = A0 + 16 * 256;
#pragma unroll
    for (int ks = 0; ks < 8; ++ks) {
      const int ib = ((ks & 1) ? (be ^ 32) : be) + ks * 2048;
      bf16x8 bf[4];
#pragma unroll
      for (int pb = 0; pb < 4; ++pb) bf[pb] = *(const bf16x8*)(&XF[ib + pb * 128]);
      bf16x8 a0 = *(const bf16x8*)(A0 + ks * 32 + g * 8);
      bf16x8 a1 = *(const bf16x8*)(A1r + ks * 32 + g * 8);
#pragma unroll
      for (int pb = 0; pb < 4; ++pb) {
        accA[0][pb] = __builtin_amdgcn_mfma_f32_16x16x32_bf16(a0, bf[pb], accA[0][pb], 0, 0, 0);
        accA[1][pb] = __builtin_amdgcn_mfma_f32_16x16x32_bf16(a1, bf[pb], accA[1][pb], 0, 0, 0);
      }
    }
  }

  // ---- y = a * silu(bb) -> SF ----
#pragma unroll
  for (int rf = 0; rf < 2; ++rf) {
    const int r0 = wrow + rf * 16 + g * 4;
    const int ydblk = r0 >> 3;
    const int ys = ydblk & 7;
    const int yoff = (g & 1) * 4;
#pragma unroll
    for (int pb = 0; pb < 4; ++pb) {
      const int p = pb * 16 + li;
      f32x4 aa = accA[rf][pb], bb = accB[rf][pb];
      float y0 = aa[0] * (bb[0] / (1.f + __expf(-bb[0])));
      float y1 = aa[1] * (bb[1] / (1.f + __expf(-bb[1])));
      float y2 = aa[2] * (bb[2] / (1.f + __expf(-bb[2])));
      float y3 = aa[3] * (bb[3] / (1.f + __expf(-bb[3])));
      const int idx = ydblk * 512 + ((p ^ ys) * 8) + yoff;
      uint2 w;
      w.x = pack2(y0, y1);
      w.y = pack2(y2, y3);
      *(uint2*)(&SF[idx]) = w;
    }
  }
  __syncthreads();

  // ---- GEMM3': out = [A3 | gsum*Wp] @ [y; x]  (K = 512) ----
  f32x4 accO[2][4];
#pragma unroll
  for (int rf = 0; rf < 2; ++rf)
#pragma unroll
    for (int pb = 0; pb < 4; ++pb) accO[rf][pb] = (f32x4)0.f;
  {
    const unsigned short* A0 = A3b + ((size_t)b * 256 + wrow + li) * 512;
    const unsigned short* A1r = A0 + 16 * 512;
#pragma unroll
    for (int ks = 0; ks < 16; ++ks) {
      const int kk = ks & 7;
      const unsigned short* Bsrc = (ks < 8) ? SF : XF;
      const int ib = ((kk & 1) ? (be ^ 32) : be) + kk * 2048;
      bf16x8 bf[4];
#pragma unroll
      for (int pb = 0; pb < 4; ++pb) bf[pb] = *(const bf16x8*)(&Bsrc[ib + pb * 128]);
      bf16x8 a0 = *(const bf16x8*)(A0 + ks * 32 + g * 8);
      bf16x8 a1 = *(const bf16x8*)(A1r + ks * 32 + g * 8);
#pragma unroll
      for (int pb = 0; pb < 4; ++pb) {
        accO[0][pb] = __builtin_amdgcn_mfma_f32_16x16x32_bf16(a0, bf[pb], accO[0][pb], 0, 0, 0);
        accO[1][pb] = __builtin_amdgcn_mfma_f32_16x16x32_bf16(a1, bf[pb], accO[1][pb], 0, 0, 0);
      }
    }
  }

  // ---- store out (fp32) ----
  float* obase = out + pbase;
#pragma unroll
  for (int rf = 0; rf < 2; ++rf) {
    const int r0 = wrow + rf * 16 + g * 4;
#pragma unroll
    for (int pb = 0; pb < 4; ++pb) {
      const int p = pb * 16 + li;
#pragma unroll
      for (int i = 0; i < 4; ++i)
        obase[(size_t)(r0 + i) * HW + p] = accO[rf][pb][i];
    }
  }
}

// ---------------------------------------------------------------------------
extern "C" void kernel_launch(void* const* d_in, const int* in_sizes, int n_in,
                              void* d_out, int out_size, void* d_ws, size_t ws_size,
                              hipStream_t stream) {
  (void)in_sizes; (void)n_in; (void)out_size; (void)ws_size;
  const float* x   = (const float*)d_in[0];
  const float* shr = (const float*)d_in[1];
  const float* w1  = (const float*)d_in[2];
  const float* b1  = (const float*)d_in[3];
  const float* w2  = (const float*)d_in[4];
  const float* b2  = (const float*)d_in[5];
  const float* gw  = (const float*)d_in[6];
  const float* fgw = (const float*)d_in[7];
  const float* p0  = (const float*)d_in[8];
  const float* p1  = (const float*)d_in[9];
  const float* p2  = (const float*)d_in[10];
  const float* wp  = (const float*)d_in[11];
  float* out = (float*)d_out;

  float* ws    = (float*)d_ws;
  float* xsum  = ws;                         // 2048 f32
  float* hsum  = ws + 2048;                  // 2048 f32
  float* gates = ws + 4096;                  // 32 f32
  float* gsumv = ws + 4128;                  // 8 f32
  int*   sel   = (int*)(ws + 4136);          // 16 ints
  float* q2    = ws + 4152;                  // 131072 f32
  unsigned* A1u = (unsigned*)(ws + 135224);  // 262144 u32 (bf16 pairs)
  unsigned* A2u = A1u + NB * 256 * 128;      // 262144 u32
  unsigned* A3u = A2u + NB * 256 * 128;      // 524288 u32
  float* t1g   = (float*)(A3u + NB * 256 * 256);  // 4096 f32
  float* feg   = t1g + NB * HID;                  // 2048 f32

  k_conv_reduce<<<NB * DIMC, 256, 0, stream>>>(x, xsum, hsum);
  k_gate_t1<<<1024, 256, 0, stream>>>(hsum, w1, b1, t1g);
  k_gate_fe<<<512, 256, 0, stream>>>(t1g, w2, b2, feg);
  k_gate_fin<<<1, 256, 0, stream>>>(xsum, feg, gw, fgw, gates, gsumv, sel);
  k_q2<<<NE * DIMC, 128, 0, stream>>>(wp, p2, q2);
  k_build<<<512, 256, 0, stream>>>(p0, p1, wp, q2, gates, gsumv, sel, A1u, A2u, A3u);
  k_main_mfma<<<2048, 512, 0, stream>>>(x, shr,
      (const unsigned short*)A1u, (const unsigned short*)A2u,
      (const unsigned short*)A3u, out);
}